// Round 6
// baseline (199.594 us; speedup 1.0000x reference)
//
#include <hip/hip_runtime.h>

// GCN on 100K nodes / 1.6M edges; output depends only on node_index's 3-hop
// in-neighborhood. v7: dispatch-count attack via ticket/last-blocks chaining.
// Post-mortems driving this design:
//  - v4: cooperative grid.sync = ~120us/sync (L2 invalidation storm). NEVER
//    full-grid barrier.
//  - v5: layer-2 on ONE block = 59us latency serial. Keep phase parallelism.
//  - v6 counters: all our kernels < fill(42us); budget fit says ~9us/launch
//    overhead x 9 dispatches dominates. => fewer dispatches, same parallelism.
// Mechanism: after phase work, each block __threadfence()s and takes a ticket
// (device-scope fetch_add). Blocks with the top-K tickets have ALREADY
// finished their own work, so spinning (acquire, s_sleep backoff) is
// deadlock-free regardless of scheduling; they then run the next phase with
// K-block parallelism (K=128 for L1 rows, K=8 for L2 rows, K=1 for tail).
// Also: slot maps use "slot+1, 0=empty" so ALL state zero-inits -> ONE memset.
// 5 dispatches: memset, scanF1, scanF2, scanS, compute.

#define HID  64
#define CAP1 2048   // compact rows for F2 (layer-1 outputs)
#define CAP2 512    // compact rows for F1 (layer-2 outputs)
#define RB1  128    // per-row in-edge bucket depth, layer 1
#define RB2  128    // per-row in-edge bucket depth, layer 2
#define CL3  2048   // layer-3 edge list capacity
#define VE   8      // edges per thread per chunk
#define TPB  256
#define GC   256    // compute-kernel grid (blocks)
#define NL1  128    // blocks continuing into layer-1 (512 waves)
#define NL2  8      // blocks continuing into layer-2 (32 waves)

// wave-level dtype probe: high dwords of first 64 entries all zero -> int64
__device__ __forceinline__ int detect64(const void* ei) {
  const unsigned* e32 = (const unsigned*)ei;
  int lane = threadIdx.x & 63;
  bool z = (e32[2 * lane + 1] == 0u);
  return (__ballot(z) == ~0ull) ? 1 : 0;
}

__device__ __forceinline__ int ld_src(const void* ei, int is64, long long e) {
  return is64 ? (int)((const unsigned*)ei)[e << 1] : ((const int*)ei)[e];
}

// load up to VE dst values from the raw edge index (scanF1 only)
__device__ __forceinline__ int load_dsts(const void* ei, long long E, long long base,
                                         int is64, int d[VE]) {
  int n = (int)((E - base) < VE ? (E - base) : VE);
  if (is64) {
    const unsigned long long* p = (const unsigned long long*)ei + E + base;
    if (n == VE && (((E + base) & 1) == 0)) {
      const ulonglong2* q = (const ulonglong2*)p;
#pragma unroll
      for (int k = 0; k < VE / 2; ++k) {
        ulonglong2 v = q[k];
        d[2 * k] = (int)(unsigned)v.x; d[2 * k + 1] = (int)(unsigned)v.y;
      }
    } else {
      for (int k = 0; k < n; ++k) d[k] = (int)(unsigned)p[k];
    }
  } else {
    const int* p = (const int*)ei + E + base;
    if (n == VE && (((E + base) & 3) == 0)) {
      const int4* q = (const int4*)p;
#pragma unroll
      for (int k = 0; k < VE / 4; ++k) {
        int4 v = q[k];
        d[4 * k] = v.x; d[4 * k + 1] = v.y; d[4 * k + 2] = v.z; d[4 * k + 3] = v.w;
      }
    } else {
      for (int k = 0; k < n; ++k) d[k] = p[k];
    }
  }
  return n;
}

// load up to VE dst values from the compacted int32 array
__device__ __forceinline__ int load_dsts32(const int* dst32, long long E,
                                           long long base, int d[VE]) {
  int n = (int)((E - base) < VE ? (E - base) : VE);
  if (n == VE) {  // base is a multiple of VE -> 16B aligned
    int4 a = ((const int4*)(dst32 + base))[0];
    int4 b = ((const int4*)(dst32 + base))[1];
    d[0] = a.x; d[1] = a.y; d[2] = a.z; d[3] = a.w;
    d[4] = b.x; d[5] = b.y; d[6] = b.z; d[7] = b.w;
  } else {
    for (int k = 0; k < n; ++k) d[k] = dst32[base + k];
  }
  return n;
}

// slot maps: 0 = empty, -1 = claim in progress, v>0 = row v-1.
// Claims are CAS(0,-1) then store p+1. Values are never read in the same
// dispatch that claims them, so the transient -1 is never observed by users.

// F1 discovery (dst == n0) + n0 seeding + dst32 compaction + layer-3 list.
__global__ void k_scanF1(const void* ei, int E, const int* nidx_p, int* dst32,
                         int* slot2, int* node2, int* cnt2, int* l3, int* ec3) {
  int is64 = detect64(ei);
  int nidx = *nidx_p;
  if (blockIdx.x == 0 && threadIdx.x == 0) {  // seed n0 into F1 (CAS-safe)
    if (atomicCAS(&slot2[nidx], 0, -1) == 0) {
      int p = atomicAdd(cnt2, 1) & (CAP2 - 1);
      slot2[nidx] = p + 1; node2[p] = nidx;
    }
  }
  long long base = ((long long)blockIdx.x * TPB + threadIdx.x) * VE;
  if (base >= E) return;
  int d[VE];
  int n = load_dsts(ei, E, base, is64, d);
  if (n == VE) {
    ((int4*)(dst32 + base))[0] = make_int4(d[0], d[1], d[2], d[3]);
    ((int4*)(dst32 + base))[1] = make_int4(d[4], d[5], d[6], d[7]);
  } else {
    for (int k = 0; k < n; ++k) dst32[base + k] = d[k];
  }
  for (int k = 0; k < n; ++k) {
    if (d[k] == nidx) {
      int s = ld_src(ei, is64, base + k);
      if (atomicCAS(&slot2[s], 0, -1) == 0) {
        int p = atomicAdd(cnt2, 1) & (CAP2 - 1);
        slot2[s] = p + 1; node2[p] = s;
      }
      int q = atomicAdd(ec3, 1);
      if (q < CL3) l3[q] = s;
    }
  }
}

// F2 discovery: prologue propagates F1 -> slot1 (+need); main loop claims
// sources of F1-dst edges and buckets them per F1 row.
__global__ void k_scanF2(const void* ei, int E, const int* dst32,
                         const int* slot2, const int* node2, const int* cnt2,
                         int* slot1, int* node1, int* need, int* cnt1,
                         int* rc2, int* bl2) {
  int rows2 = min(*cnt2, CAP2);
  for (int r = threadIdx.x; r < rows2; r += TPB) {
    int i = node2[r];
    need[i] = 1;
    if (atomicCAS(&slot1[i], 0, -1) == 0) {
      int p = atomicAdd(cnt1, 1) & (CAP1 - 1);
      slot1[i] = p + 1; node1[p] = i;
    }
  }
  int is64 = detect64(ei);
  long long base = ((long long)blockIdx.x * TPB + threadIdx.x) * VE;
  if (base >= E) return;
  int d[VE];
  int n = load_dsts32(dst32, E, base, d);
  for (int k = 0; k < n; ++k) {
    int sv = slot2[d[k]];
    if (sv > 0) {
      int ad = sv - 1;
      int s = ld_src(ei, is64, base + k);
      need[s] = 1;
      if (atomicCAS(&slot1[s], 0, -1) == 0) {
        int p = atomicAdd(cnt1, 1) & (CAP1 - 1);
        slot1[s] = p + 1; node1[p] = s;
      }
      int q = atomicAdd(&rc2[ad], 1);
      if (q < RB2) bl2[ad * RB2 + q] = s;
    }
  }
}

// S marking + layer-1 buckets: edges with dst in F2.
__global__ void k_scanS(const void* ei, int E, const int* dst32,
                        const int* slot1, int* need, int* rc1, int* bl1) {
  int is64 = detect64(ei);
  long long base = ((long long)blockIdx.x * TPB + threadIdx.x) * VE;
  if (base >= E) return;
  int d[VE];
  int n = load_dsts32(dst32, E, base, d);
  for (int k = 0; k < n; ++k) {
    int sv = slot1[d[k]];
    if (sv > 0) {
      int ad = sv - 1;
      int s = ld_src(ei, is64, base + k);
      need[s] = 1;
      int q = atomicAdd(&rc1[ad], 1);
      if (q < RB1) bl1[ad * RB1 + q] = s;
    }
  }
}

// fused: deg histogram -> (128 blocks) layer 1 -> (8 blocks) layer 2 ->
// (1 block) layer 3 + head. Ticket chaining; spinners already finished work.
__global__ __launch_bounds__(TPB) void k_compute(
    int E, const int* __restrict__ dst32, const int* __restrict__ need,
    int* __restrict__ deg,
    const float* __restrict__ x, const float* __restrict__ W1,
    const float* __restrict__ b1, const int* __restrict__ node1,
    const int* __restrict__ cnt1, const int* __restrict__ rc1,
    const int* __restrict__ bl1, float* __restrict__ h1c,
    const float* __restrict__ W2, const float* __restrict__ b2,
    const int* __restrict__ node2, const int* __restrict__ cnt2,
    const int* __restrict__ slot1, const int* __restrict__ rc2,
    const int* __restrict__ bl2, float* __restrict__ h2c,
    const int* __restrict__ nidx_p, const int* __restrict__ slot2,
    const int* __restrict__ l3, const int* __restrict__ ec3,
    const float* __restrict__ W3, const float* __restrict__ b3,
    const float* __restrict__ Wp, const float* __restrict__ bp,
    const float* __restrict__ Wa, const float* __restrict__ ba,
    const float* __restrict__ Wm, const float* __restrict__ bm,
    const float* __restrict__ Wg, const float* __restrict__ bg,
    const float* __restrict__ Wt, const float* __restrict__ bt,
    float* __restrict__ out,
    int* tickD, int* tickL1, int* tickL2) {
  const int tid = threadIdx.x;
  const int lane = tid & 63, wv = tid >> 6;
  __shared__ int s_t;
  __shared__ float sh[4][HID];
  __shared__ float g3[HID];
  __shared__ float h3v[HID];
  __shared__ float pj[HID];
  __shared__ int   ssl[64];
  __shared__ float scc[64];

  // ---- phase D: need-filtered degree histogram (all GC blocks) ----
  for (long long base = ((long long)blockIdx.x * TPB + tid) * VE;
       base < E; base += (long long)GC * TPB * VE) {
    int d[VE]; int n = load_dsts32(dst32, E, base, d);
    for (int k = 0; k < n; ++k)
      if (need[d[k]]) atomicAdd(&deg[d[k]], 1);
  }
  __syncthreads();
  if (tid == 0) {
    __threadfence();
    s_t = __hip_atomic_fetch_add(tickD, 1, __ATOMIC_ACQ_REL,
                                 __HIP_MEMORY_SCOPE_AGENT);
  }
  __syncthreads();
  int t = s_t;
  if (t < GC - NL1) return;  // not in L1 group
  if (tid == 0) {
    while (__hip_atomic_load(tickD, __ATOMIC_ACQUIRE,
                             __HIP_MEMORY_SCOPE_AGENT) < GC)
      __builtin_amdgcn_s_sleep(2);
  }
  __syncthreads();

  // ---- phase L1: one wave per F2 row (factorized) ----
  {
    int r1 = t - (GC - NL1);  // 0..NL1-1
    int rows1 = min(*cnt1, CAP1);
    for (int w = r1 * 4 + wv; w < rows1; w += NL1 * 4) {
      int i = node1[w];
      float di = 1.0f / sqrtf((float)(deg[i] + 1));
      int cnt = min(rc1[w], RB1);
      float ax = 0.f, ay = 0.f, az = 0.f, aw = 0.f;
      for (int j = lane; j < cnt; j += 64) {
        int s = bl1[w * RB1 + j];
        float c = (1.0f / sqrtf((float)(deg[s] + 1))) * di;
        float4 xv = ((const float4*)x)[s];
        ax += c * xv.x; ay += c * xv.y; az += c * xv.z; aw += c * xv.w;
      }
#pragma unroll
      for (int u = 1; u < 64; u <<= 1) {
        ax += __shfl_xor(ax, u); ay += __shfl_xor(ay, u);
        az += __shfl_xor(az, u); aw += __shfl_xor(aw, u);
      }
      float4 xi = ((const float4*)x)[i];
      float dd = di * di;
      ax += dd * xi.x; ay += dd * xi.y; az += dd * xi.z; aw += dd * xi.w;
      float v = ax * W1[lane] + ay * W1[64 + lane] + az * W1[128 + lane] +
                aw * W1[192 + lane] + b1[lane];
      h1c[w * HID + lane] = v > 0.f ? v : 0.f;
    }
  }
  __syncthreads();
  if (tid == 0) {
    __threadfence();
    s_t = __hip_atomic_fetch_add(tickL1, 1, __ATOMIC_ACQ_REL,
                                 __HIP_MEMORY_SCOPE_AGENT);
  }
  __syncthreads();
  t = s_t;
  if (t < NL1 - NL2) return;  // not in L2 group
  if (tid == 0) {
    while (__hip_atomic_load(tickL1, __ATOMIC_ACQUIRE,
                             __HIP_MEMORY_SCOPE_AGENT) < NL1)
      __builtin_amdgcn_s_sleep(2);
  }
  __syncthreads();

  // ---- phase L2: one wave per F1 row ----
  int rows2 = min(*cnt2, CAP2);
  {
    int r2 = t - (NL1 - NL2);  // 0..NL2-1
    for (int w = r2 * 4 + wv; w < rows2; w += NL2 * 4) {
      int i = node2[w];
      float di = 1.0f / sqrtf((float)(deg[i] + 1));
      int cnt = min(rc2[w], RB2);
      float acc = 0.f;
      for (int j0 = 0; j0 < cnt; j0 += 64) {
        int nb = min(64, cnt - j0);
        int sl = 0; float c = 0.f;
        if (lane < nb) {
          int s = bl2[w * RB2 + j0 + lane];
          sl = slot1[s] - 1;
          c = (1.0f / sqrtf((float)(deg[s] + 1))) * di;
        }
        for (int j = 0; j < nb; ++j) {
          int slj = __shfl(sl, j);
          float cj = __shfl(c, j);
          acc += cj * h1c[slj * HID + lane];
        }
      }
      acc += di * di * h1c[(slot1[i] - 1) * HID + lane];
      sh[wv][lane] = acc;  // same-wave write->read (lockstep)
      float v = b2[lane];
#pragma unroll 16
      for (int k = 0; k < HID; ++k) v += sh[wv][k] * W2[k * HID + lane];
      h2c[w * HID + lane] = v > 0.f ? v : 0.f;
    }
  }
  __syncthreads();
  if (tid == 0) {
    __threadfence();
    s_t = __hip_atomic_fetch_add(tickL2, 1, __ATOMIC_ACQ_REL,
                                 __HIP_MEMORY_SCOPE_AGENT);
  }
  __syncthreads();
  t = s_t;
  if (t != NL2 - 1) return;  // only the LAST L2 block runs the tail

  // ---- tail: layer-3 aggregate + head MLP + 4 projections (one block) ----
  {
    int nidx = *nidx_p;
    float dn = 1.0f / sqrtf((float)(deg[nidx] + 1));
    int cnt = min(*ec3, CL3);
    float acc = 0.f;
    for (int j0 = 0; j0 < cnt; j0 += 64) {
      int nb = min(64, cnt - j0);
      if (tid < nb) {
        int s = l3[j0 + tid];
        ssl[tid] = slot2[s] - 1;
        scc[tid] = (1.0f / sqrtf((float)(deg[s] + 1))) * dn;
      }
      __syncthreads();
      for (int j = wv; j < nb; j += 4)
        acc += scc[j] * h2c[ssl[j] * HID + lane];
      __syncthreads();
    }
    sh[wv][lane] = acc;
    __syncthreads();
    if (wv == 0) {
      float a = sh[0][lane] + sh[1][lane] + sh[2][lane] + sh[3][lane];
      a += dn * dn * h2c[(slot2[nidx] - 1) * HID + lane];
      g3[lane] = a;
    }
    __syncthreads();
    if (wv == 0) {
      float v = b3[lane];
#pragma unroll 16
      for (int k = 0; k < HID; ++k) v += g3[k] * W3[k * HID + lane];
      h3v[lane] = v > 0.f ? v : 0.f;
    }
    __syncthreads();
    if (wv == 0) {
      float v = bp[lane];
#pragma unroll 16
      for (int k = 0; k < HID; ++k) v += h3v[k] * Wp[k * HID + lane];
      pj[lane] = v > 0.f ? v : 0.f;
    }
    __syncthreads();
    if (tid < 4) {
      float o = ba[tid];
      for (int k = 0; k < HID; ++k) o += pj[k] * Wa[k * 4 + tid];
      out[tid] = o;
    } else if (tid < 6) {
      int c = tid - 4; float o = bm[c];
      for (int k = 0; k < HID; ++k) o += pj[k] * Wm[k * 2 + c];
      out[tid] = o;
    } else if (tid < 9) {
      int c = tid - 6; float o = bg[c];
      for (int k = 0; k < HID; ++k) o += pj[k] * Wg[k * 3 + c];
      out[tid] = o;
    } else if (tid < 19) {
      int c = tid - 9; float o = bt[c];
      for (int k = 0; k < HID; ++k) o += pj[k] * Wt[k * 10 + c];
      out[tid] = o;
    }
  }
}

extern "C" void kernel_launch(void* const* d_in, const int* in_sizes, int n_in,
                              void* d_out, int out_size, void* d_ws, size_t ws_size,
                              hipStream_t stream) {
  const float* x  = (const float*)d_in[0];
  const void*  ei = d_in[1];
  const int* nidx = (const int*)d_in[2];
  const float* W1 = (const float*)d_in[3];
  const float* b1 = (const float*)d_in[4];
  const float* W2 = (const float*)d_in[5];
  const float* b2 = (const float*)d_in[6];
  const float* W3 = (const float*)d_in[7];
  const float* b3 = (const float*)d_in[8];
  const float* Wp = (const float*)d_in[9];
  const float* bp = (const float*)d_in[10];
  const float* Wa = (const float*)d_in[11];
  const float* ba = (const float*)d_in[12];
  const float* Wm = (const float*)d_in[13];
  const float* bm = (const float*)d_in[14];
  const float* Wg = (const float*)d_in[15];
  const float* bg = (const float*)d_in[16];
  const float* Wt = (const float*)d_in[17];
  const float* bt = (const float*)d_in[18];
  float* out = (float*)d_out;

  int N = in_sizes[0] / 4;   // 100000
  int E = in_sizes[1] / 2;   // 1600000

  char* w = (char*)d_ws;
  size_t o = 0;
  auto take = [&](size_t bytes) -> void* {
    void* p = w + o;
    o += (bytes + 255) & ~(size_t)255;
    return p;
  };
  // single zero region: counters/tickets, deg, need, rc1, rc2, slot1, slot2
  size_t zeroInts = (size_t)(8 + 2 * N + CAP1 + CAP2) + (size_t)2 * N;
  int* zr = (int*)take(zeroInts * 4);
  int* cnt1  = zr + 0;
  int* cnt2  = zr + 1;
  int* ec3   = zr + 2;
  int* tickD = zr + 3;
  int* tickL1= zr + 4;
  int* tickL2= zr + 5;
  int* deg   = zr + 8;
  int* need  = deg + N;
  int* rc1   = need + N;
  int* rc2   = rc1 + CAP1;
  int* slot1 = rc2 + CAP2;
  int* slot2 = slot1 + N;
  int*   dst32 = (int*)take((size_t)E * 4);
  int*   node1 = (int*)take((size_t)CAP1 * 4);
  int*   node2 = (int*)take((size_t)CAP2 * 4);
  int*   bl1   = (int*)take((size_t)CAP1 * RB1 * 4);
  int*   bl2   = (int*)take((size_t)CAP2 * RB2 * 4);
  int*   l3    = (int*)take((size_t)CL3 * 4);
  float* h1c   = (float*)take((size_t)CAP1 * HID * 4);
  float* h2c   = (float*)take((size_t)CAP2 * HID * 4);

  int gS = (int)(((long long)E + TPB * VE - 1) / (TPB * VE));

  hipMemsetAsync(zr, 0x00, zeroInts * 4, stream);
  k_scanF1 <<<gS, TPB, 0, stream>>>(ei, E, nidx, dst32, slot2, node2, cnt2, l3, ec3);
  k_scanF2 <<<gS, TPB, 0, stream>>>(ei, E, dst32, slot2, node2, cnt2,
                                    slot1, node1, need, cnt1, rc2, bl2);
  k_scanS  <<<gS, TPB, 0, stream>>>(ei, E, dst32, slot1, need, rc1, bl1);
  k_compute<<<GC, TPB, 0, stream>>>(E, dst32, need, deg,
                                    x, W1, b1, node1, cnt1, rc1, bl1, h1c,
                                    W2, b2, node2, cnt2, slot1, rc2, bl2, h2c,
                                    nidx, slot2, l3, ec3, W3, b3, Wp, bp,
                                    Wa, ba, Wm, bm, Wg, bg, Wt, bt, out,
                                    tickD, tickL1, tickL2);
}

// Round 7
// 170.173 us; speedup vs baseline: 1.1729x; 1.1729x over previous
//
#include <hip/hip_runtime.h>

// GCN on 100K nodes / 1.6M edges; output depends only on node_index's 3-hop
// in-neighborhood. v8 = v6 skeleton + latency-ILP in gathers + 1 memset.
// Post-mortem ledger:
//  - v4: cooperative grid.sync ~120us/sync. Never full-grid barrier.
//  - v5: l2+tail on ONE block serialized rows -> 59us. Keep row parallelism.
//  - v7: in-kernel ticket barriers ~15us/boundary (same-address agent-scope
//    RMW serialization + threadfence) — WORSE than an 8us dispatch boundary.
//    Dispatch count floor is the pipeline depth: 8 sequential stages.
//  - remaining device cost: serial L2-miss chains in k_l2/k_tail gathers
//    (~0.4us per un-batched row load, v5 measurement). Fix: batch 8/4
//    independent loads before the FMAs; wave-split tail matvecs.
// Stages: memset -> scanF1 -> scanF2 -> scanS -> scanDeg -> l1 -> l2 -> tail.
//   F1 = in(n0) u {n0}   (~17)   -> rows node2/slot2 -> h2c
//   F2 = in(F1) u F1     (~290)  -> rows node1/slot1 -> h1c
//   S  = F2 u in(F2)     (~5K)   -> need[]: degree targets
// slot maps: 0=empty, -1=claim-in-progress, v>0 = row v-1 (zero-init only).

#define HID  64
#define CAP1 2048   // compact rows for F2 (layer-1 outputs)
#define CAP2 512    // compact rows for F1 (layer-2 outputs)
#define RB1  128    // per-row in-edge bucket depth, layer 1
#define RB2  128    // per-row in-edge bucket depth, layer 2
#define CL3  2048   // layer-3 edge list capacity
#define VE   8      // edges per thread in scans
#define TPB  256

// wave-level dtype probe: high dwords of first 64 entries all zero -> int64
__device__ __forceinline__ int detect64(const void* ei) {
  const unsigned* e32 = (const unsigned*)ei;
  int lane = threadIdx.x & 63;
  bool z = (e32[2 * lane + 1] == 0u);
  return (__ballot(z) == ~0ull) ? 1 : 0;
}

__device__ __forceinline__ int ld_src(const void* ei, int is64, long long e) {
  return is64 ? (int)((const unsigned*)ei)[e << 1] : ((const int*)ei)[e];
}

// load up to VE dst values from the raw edge index (scanF1 only)
__device__ __forceinline__ int load_dsts(const void* ei, long long E, long long base,
                                         int is64, int d[VE]) {
  int n = (int)((E - base) < VE ? (E - base) : VE);
  if (is64) {
    const unsigned long long* p = (const unsigned long long*)ei + E + base;
    if (n == VE && (((E + base) & 1) == 0)) {
      const ulonglong2* q = (const ulonglong2*)p;
#pragma unroll
      for (int k = 0; k < VE / 2; ++k) {
        ulonglong2 v = q[k];
        d[2 * k] = (int)(unsigned)v.x; d[2 * k + 1] = (int)(unsigned)v.y;
      }
    } else {
      for (int k = 0; k < n; ++k) d[k] = (int)(unsigned)p[k];
    }
  } else {
    const int* p = (const int*)ei + E + base;
    if (n == VE && (((E + base) & 3) == 0)) {
      const int4* q = (const int4*)p;
#pragma unroll
      for (int k = 0; k < VE / 4; ++k) {
        int4 v = q[k];
        d[4 * k] = v.x; d[4 * k + 1] = v.y; d[4 * k + 2] = v.z; d[4 * k + 3] = v.w;
      }
    } else {
      for (int k = 0; k < n; ++k) d[k] = p[k];
    }
  }
  return n;
}

// load up to VE dst values from the compacted int32 array (scans 2-4)
__device__ __forceinline__ int load_dsts32(const int* dst32, long long E,
                                           long long base, int d[VE]) {
  int n = (int)((E - base) < VE ? (E - base) : VE);
  if (n == VE) {  // base is a multiple of VE -> 16B aligned
    int4 a = ((const int4*)(dst32 + base))[0];
    int4 b = ((const int4*)(dst32 + base))[1];
    d[0] = a.x; d[1] = a.y; d[2] = a.z; d[3] = a.w;
    d[4] = b.x; d[5] = b.y; d[6] = b.z; d[7] = b.w;
  } else {
    for (int k = 0; k < n; ++k) d[k] = dst32[base + k];
  }
  return n;
}

// F1 discovery (dst == n0) + n0 seeding + dst32 compaction + layer-3 list.
__global__ void k_scanF1(const void* ei, int E, const int* nidx_p, int* dst32,
                         int* slot2, int* node2, int* cnt2, int* l3, int* ec3) {
  int is64 = detect64(ei);
  int nidx = *nidx_p;
  if (blockIdx.x == 0 && threadIdx.x == 0) {  // seed n0 into F1 (CAS-safe)
    if (atomicCAS(&slot2[nidx], 0, -1) == 0) {
      int p = atomicAdd(cnt2, 1) & (CAP2 - 1);
      slot2[nidx] = p + 1; node2[p] = nidx;
    }
  }
  long long base = ((long long)blockIdx.x * TPB + threadIdx.x) * VE;
  if (base >= E) return;
  int d[VE];
  int n = load_dsts(ei, E, base, is64, d);
  if (n == VE) {
    ((int4*)(dst32 + base))[0] = make_int4(d[0], d[1], d[2], d[3]);
    ((int4*)(dst32 + base))[1] = make_int4(d[4], d[5], d[6], d[7]);
  } else {
    for (int k = 0; k < n; ++k) dst32[base + k] = d[k];
  }
  for (int k = 0; k < n; ++k) {
    if (d[k] == nidx) {
      int s = ld_src(ei, is64, base + k);
      if (atomicCAS(&slot2[s], 0, -1) == 0) {
        int p = atomicAdd(cnt2, 1) & (CAP2 - 1);
        slot2[s] = p + 1; node2[p] = s;
      }
      int q = atomicAdd(ec3, 1);
      if (q < CL3) l3[q] = s;
    }
  }
}

// F2 discovery: prologue propagates F1 -> slot1 (+need); main loop claims
// sources of F1-dst edges and buckets them per F1 row. slot1 VALUES are
// never read in this dispatch, so cross-block CAS claims are safe.
__global__ void k_scanF2(const void* ei, int E, const int* dst32,
                         const int* slot2, const int* node2, const int* cnt2,
                         int* slot1, int* node1, int* need, int* cnt1,
                         int* rc2, int* bl2) {
  int rows2 = min(*cnt2, CAP2);
  for (int r = threadIdx.x; r < rows2; r += TPB) {
    int i = node2[r];
    need[i] = 1;
    if (atomicCAS(&slot1[i], 0, -1) == 0) {
      int p = atomicAdd(cnt1, 1) & (CAP1 - 1);
      slot1[i] = p + 1; node1[p] = i;
    }
  }
  int is64 = detect64(ei);
  long long base = ((long long)blockIdx.x * TPB + threadIdx.x) * VE;
  if (base >= E) return;
  int d[VE];
  int n = load_dsts32(dst32, E, base, d);
  for (int k = 0; k < n; ++k) {
    int sv = slot2[d[k]];
    if (sv > 0) {
      int ad = sv - 1;
      int s = ld_src(ei, is64, base + k);
      need[s] = 1;
      if (atomicCAS(&slot1[s], 0, -1) == 0) {
        int p = atomicAdd(cnt1, 1) & (CAP1 - 1);
        slot1[s] = p + 1; node1[p] = s;
      }
      int q = atomicAdd(&rc2[ad], 1);
      if (q < RB2) bl2[ad * RB2 + q] = s;
    }
  }
}

// S marking + layer-1 buckets: edges with dst in F2.
__global__ void k_scanS(const void* ei, int E, const int* dst32,
                        const int* slot1, int* need, int* rc1, int* bl1) {
  int is64 = detect64(ei);
  long long base = ((long long)blockIdx.x * TPB + threadIdx.x) * VE;
  if (base >= E) return;
  int d[VE];
  int n = load_dsts32(dst32, E, base, d);
  for (int k = 0; k < n; ++k) {
    int sv = slot1[d[k]];
    if (sv > 0) {
      int ad = sv - 1;
      int s = ld_src(ei, is64, base + k);
      need[s] = 1;
      int q = atomicAdd(&rc1[ad], 1);
      if (q < RB1) bl1[ad * RB1 + q] = s;
    }
  }
}

// need-filtered degree histogram (~80K atomics over ~5K addresses)
__global__ void k_scanDeg(int E, const int* dst32, const int* need, int* deg) {
  long long base = ((long long)blockIdx.x * TPB + threadIdx.x) * VE;
  if (base >= E) return;
  int d[VE];
  int n = load_dsts32(dst32, E, base, d);
  for (int k = 0; k < n; ++k)
    if (need[d[k]]) atomicAdd(&deg[d[k]], 1);
}

// layer 1, one wave per F2 row (factorized: neighbor-sum then one matvec).
// Per-lane bucket loads are already independent (latency overlapped).
__global__ void k_l1(const float* __restrict__ x, const float* __restrict__ W1,
                     const float* __restrict__ b1, const int* __restrict__ deg,
                     const int* __restrict__ node1, const int* __restrict__ cnt1,
                     const int* __restrict__ rc1, const int* __restrict__ bl1,
                     float* __restrict__ h1c) {
  int w = blockIdx.x * 4 + (threadIdx.x >> 6);
  int lane = threadIdx.x & 63;
  int rows = min(*cnt1, CAP1);
  if (w >= rows) return;
  int i = node1[w];
  float di = 1.0f / sqrtf((float)(deg[i] + 1));
  int cnt = min(rc1[w], RB1);
  float ax = 0.f, ay = 0.f, az = 0.f, aw = 0.f;
  for (int j = lane; j < cnt; j += 64) {
    int s = bl1[w * RB1 + j];
    float c = (1.0f / sqrtf((float)(deg[s] + 1))) * di;
    float4 xv = ((const float4*)x)[s];
    ax += c * xv.x; ay += c * xv.y; az += c * xv.z; aw += c * xv.w;
  }
#pragma unroll
  for (int t = 1; t < 64; t <<= 1) {
    ax += __shfl_xor(ax, t); ay += __shfl_xor(ay, t);
    az += __shfl_xor(az, t); aw += __shfl_xor(aw, t);
  }
  float4 xi = ((const float4*)x)[i];
  float dd = di * di;
  ax += dd * xi.x; ay += dd * xi.y; az += dd * xi.z; aw += dd * xi.w;
  float v = ax * W1[lane] + ay * W1[64 + lane] + az * W1[128 + lane] +
            aw * W1[192 + lane] + b1[lane];
  h1c[w * HID + lane] = v > 0.f ? v : 0.f;
}

// layer 2, one wave per F1 row. Gather ILP: batch 8 independent h1c row
// loads (distinct shfl'd indices) before the FMAs -> 8 misses in flight.
__global__ void k_l2(const float* __restrict__ W2, const float* __restrict__ b2,
                     const int* __restrict__ deg, const int* __restrict__ node2,
                     const int* __restrict__ cnt2, const int* __restrict__ slot1,
                     const int* __restrict__ rc2, const int* __restrict__ bl2,
                     const float* __restrict__ h1c, float* __restrict__ h2c) {
  __shared__ float sh[4][HID];
  int wv = threadIdx.x >> 6, lane = threadIdx.x & 63;
  int w = blockIdx.x * 4 + wv;
  int rows = min(*cnt2, CAP2);
  if (w >= rows) return;
  int i = node2[w];
  float di = 1.0f / sqrtf((float)(deg[i] + 1));
  int cnt = min(rc2[w], RB2);
  float acc = 0.f;
  for (int j0 = 0; j0 < cnt; j0 += 64) {
    int nb = min(64, cnt - j0);
    int sl = 0; float c = 0.f;
    if (lane < nb) {
      int s = bl2[w * RB2 + j0 + lane];
      sl = slot1[s] - 1;
      c = (1.0f / sqrtf((float)(deg[s] + 1))) * di;
    }
    int j = 0;
    for (; j + 8 <= nb; j += 8) {
      int r0 = __shfl(sl, j + 0), r1 = __shfl(sl, j + 1);
      int r2 = __shfl(sl, j + 2), r3 = __shfl(sl, j + 3);
      int r4 = __shfl(sl, j + 4), r5 = __shfl(sl, j + 5);
      int r6 = __shfl(sl, j + 6), r7 = __shfl(sl, j + 7);
      float v0 = h1c[r0 * HID + lane];
      float v1 = h1c[r1 * HID + lane];
      float v2 = h1c[r2 * HID + lane];
      float v3 = h1c[r3 * HID + lane];
      float v4 = h1c[r4 * HID + lane];
      float v5 = h1c[r5 * HID + lane];
      float v6 = h1c[r6 * HID + lane];
      float v7 = h1c[r7 * HID + lane];
      acc += __shfl(c, j + 0) * v0 + __shfl(c, j + 1) * v1 +
             __shfl(c, j + 2) * v2 + __shfl(c, j + 3) * v3 +
             __shfl(c, j + 4) * v4 + __shfl(c, j + 5) * v5 +
             __shfl(c, j + 6) * v6 + __shfl(c, j + 7) * v7;
    }
    for (; j < nb; ++j)
      acc += __shfl(c, j) * h1c[__shfl(sl, j) * HID + lane];
  }
  acc += di * di * h1c[(slot1[i] - 1) * HID + lane];
  sh[wv][lane] = acc;  // same-wave write->read (lockstep), no barrier needed
  float v = b2[lane];
#pragma unroll 16
  for (int k = 0; k < HID; ++k) v += sh[wv][k] * W2[k * HID + lane];
  h2c[w * HID + lane] = v > 0.f ? v : 0.f;
}

// layer-3 aggregate + head. Gather ILP (4 batched h2c loads per wave-step);
// W3/Wp matvecs k-split across the 4 waves + LDS reduce.
__global__ void k_tail(const int* nidx_p, const int* slot2, const int* deg,
                       const float* h2c, const int* l3, const int* ec3,
                       const float* W3, const float* b3,
                       const float* Wp, const float* bp,
                       const float* Wa, const float* ba,
                       const float* Wm, const float* bm,
                       const float* Wg, const float* bg,
                       const float* Wt, const float* bt, float* out) {
  __shared__ float part[4][HID];
  __shared__ float g3[HID];
  __shared__ float h3[HID];
  __shared__ float p[HID];
  __shared__ int   ssl[64];
  __shared__ float scc[64];
  int tid = threadIdx.x, wv = tid >> 6, lane = tid & 63;
  int nidx = *nidx_p;
  float dn = 1.0f / sqrtf((float)(deg[nidx] + 1));
  int cnt = min(*ec3, CL3);
  float acc = 0.f;
  for (int j0 = 0; j0 < cnt; j0 += 64) {
    int nb = min(64, cnt - j0);
    if (tid < nb) {
      int s = l3[j0 + tid];
      ssl[tid] = slot2[s] - 1;
      scc[tid] = (1.0f / sqrtf((float)(deg[s] + 1))) * dn;
    }
    __syncthreads();
    int j = wv;
    for (; j + 12 < nb; j += 16) {  // 4 batched loads per wave
      int r0 = ssl[j], r1 = ssl[j + 4], r2 = ssl[j + 8], r3 = ssl[j + 12];
      float v0 = h2c[r0 * HID + lane];
      float v1 = h2c[r1 * HID + lane];
      float v2 = h2c[r2 * HID + lane];
      float v3 = h2c[r3 * HID + lane];
      acc += scc[j] * v0 + scc[j + 4] * v1 + scc[j + 8] * v2 + scc[j + 12] * v3;
    }
    for (; j < nb; j += 4)
      acc += scc[j] * h2c[ssl[j] * HID + lane];
    __syncthreads();
  }
  part[wv][lane] = acc;
  __syncthreads();
  if (wv == 0) {
    float a = part[0][lane] + part[1][lane] + part[2][lane] + part[3][lane];
    a += dn * dn * h2c[(slot2[nidx] - 1) * HID + lane];
    g3[lane] = a;
  }
  __syncthreads();
  {  // h3 = relu(g3 @ W3 + b3), k-split over waves
    float v = 0.f;
    int k0 = wv * 16;
#pragma unroll 16
    for (int k = 0; k < 16; ++k) v += g3[k0 + k] * W3[(k0 + k) * HID + lane];
    part[wv][lane] = v;
  }
  __syncthreads();
  if (wv == 0) {
    float v = part[0][lane] + part[1][lane] + part[2][lane] + part[3][lane] +
              b3[lane];
    h3[lane] = v > 0.f ? v : 0.f;
  }
  __syncthreads();
  {  // p = relu(h3 @ Wp + bp), k-split over waves
    float v = 0.f;
    int k0 = wv * 16;
#pragma unroll 16
    for (int k = 0; k < 16; ++k) v += h3[k0 + k] * Wp[(k0 + k) * HID + lane];
    part[wv][lane] = v;
  }
  __syncthreads();
  if (wv == 0) {
    float v = part[0][lane] + part[1][lane] + part[2][lane] + part[3][lane] +
              bp[lane];
    p[lane] = v > 0.f ? v : 0.f;
  }
  __syncthreads();
  if (tid < 4) {
    float o = ba[tid];
#pragma unroll 8
    for (int k = 0; k < HID; ++k) o += p[k] * Wa[k * 4 + tid];
    out[tid] = o;
  } else if (tid < 6) {
    int c = tid - 4; float o = bm[c];
#pragma unroll 8
    for (int k = 0; k < HID; ++k) o += p[k] * Wm[k * 2 + c];
    out[tid] = o;
  } else if (tid < 9) {
    int c = tid - 6; float o = bg[c];
#pragma unroll 8
    for (int k = 0; k < HID; ++k) o += p[k] * Wg[k * 3 + c];
    out[tid] = o;
  } else if (tid < 19) {
    int c = tid - 9; float o = bt[c];
#pragma unroll 8
    for (int k = 0; k < HID; ++k) o += p[k] * Wt[k * 10 + c];
    out[tid] = o;
  }
}

extern "C" void kernel_launch(void* const* d_in, const int* in_sizes, int n_in,
                              void* d_out, int out_size, void* d_ws, size_t ws_size,
                              hipStream_t stream) {
  const float* x  = (const float*)d_in[0];
  const void*  ei = d_in[1];
  const int* nidx = (const int*)d_in[2];
  const float* W1 = (const float*)d_in[3];
  const float* b1 = (const float*)d_in[4];
  const float* W2 = (const float*)d_in[5];
  const float* b2 = (const float*)d_in[6];
  const float* W3 = (const float*)d_in[7];
  const float* b3 = (const float*)d_in[8];
  const float* Wp = (const float*)d_in[9];
  const float* bp = (const float*)d_in[10];
  const float* Wa = (const float*)d_in[11];
  const float* ba = (const float*)d_in[12];
  const float* Wm = (const float*)d_in[13];
  const float* bm = (const float*)d_in[14];
  const float* Wg = (const float*)d_in[15];
  const float* bg = (const float*)d_in[16];
  const float* Wt = (const float*)d_in[17];
  const float* bt = (const float*)d_in[18];
  float* out = (float*)d_out;

  int N = in_sizes[0] / 4;   // 100000
  int E = in_sizes[1] / 2;   // 1600000

  char* w = (char*)d_ws;
  size_t o = 0;
  auto take = [&](size_t bytes) -> void* {
    void* p = w + o;
    o += (bytes + 255) & ~(size_t)255;
    return p;
  };
  // single zero region: counters, deg, need, rc1, rc2, slot1, slot2
  size_t zeroInts = (size_t)8 + 2 * (size_t)N + CAP1 + CAP2 + 2 * (size_t)N;
  int* zr = (int*)take(zeroInts * 4);
  int* cnt1  = zr + 0;
  int* cnt2  = zr + 1;
  int* ec3   = zr + 2;
  int* deg   = zr + 8;
  int* need  = deg + N;
  int* rc1   = need + N;
  int* rc2   = rc1 + CAP1;
  int* slot1 = rc2 + CAP2;
  int* slot2 = slot1 + N;
  int*   dst32 = (int*)take((size_t)E * 4);
  int*   node1 = (int*)take((size_t)CAP1 * 4);
  int*   node2 = (int*)take((size_t)CAP2 * 4);
  int*   bl1   = (int*)take((size_t)CAP1 * RB1 * 4);
  int*   bl2   = (int*)take((size_t)CAP2 * RB2 * 4);
  int*   l3    = (int*)take((size_t)CL3 * 4);
  float* h1c   = (float*)take((size_t)CAP1 * HID * 4);
  float* h2c   = (float*)take((size_t)CAP2 * HID * 4);

  int gS = (int)(((long long)E + TPB * VE - 1) / (TPB * VE));

  hipMemsetAsync(zr, 0x00, zeroInts * 4, stream);
  k_scanF1 <<<gS, TPB, 0, stream>>>(ei, E, nidx, dst32, slot2, node2, cnt2, l3, ec3);
  k_scanF2 <<<gS, TPB, 0, stream>>>(ei, E, dst32, slot2, node2, cnt2,
                                    slot1, node1, need, cnt1, rc2, bl2);
  k_scanS  <<<gS, TPB, 0, stream>>>(ei, E, dst32, slot1, need, rc1, bl1);
  k_scanDeg<<<gS, TPB, 0, stream>>>(E, dst32, need, deg);
  k_l1     <<<CAP1 / 4, TPB, 0, stream>>>(x, W1, b1, deg, node1, cnt1, rc1, bl1, h1c);
  k_l2     <<<CAP2 / 4, TPB, 0, stream>>>(W2, b2, deg, node2, cnt2, slot1, rc2, bl2, h1c, h2c);
  k_tail   <<<1, TPB, 0, stream>>>(nidx, slot2, deg, h2c, l3, ec3, W3, b3, Wp, bp,
                                   Wa, ba, Wm, bm, Wg, bg, Wt, bt, out);
}

// Round 8
// 169.200 us; speedup vs baseline: 1.1796x; 1.0057x over previous
//
#include <hip/hip_runtime.h>

// GCN on 100K nodes / 1.6M edges; output depends only on node_index's 3-hop
// in-neighborhood. v9 = v8 + l2/tail re-fused on ONE 16-wave block.
// Post-mortem ledger:
//  - v4: cooperative grid.sync ~120us/sync. Never full-grid barrier.
//  - v5: l2+tail fused on 4 waves with UNBATCHED loads = 59us. Root causes:
//    serial 0.4us L2-miss chain + 17 rows / 4 waves serialization.
//  - v7: in-kernel ticket barrier ~15us/boundary > 11us dispatch. No device
//    sync; dispatch-chain depth is the floor.
//  - v8: 8-batched gather ILP verified fast in split k_l2 (not in top-5).
//  - v9: refuse l2+tail with BOTH fixes: 16 waves (1 row/wave) + 8-batch
//    ILP + loop-guards instead of early returns (all threads reach barriers).
// Stages (7): memset -> scanF1 -> scanF2 -> scanS -> scanDeg -> l1 -> l2tail.
//   F1 = in(n0) u {n0}   (~17)   -> rows node2/slot2 -> h2 (LDS)
//   F2 = in(F1) u F1     (~290)  -> rows node1/slot1 -> h1c
//   S  = F2 u in(F2)     (~5K)   -> need[]: degree targets
// slot maps: 0=empty, -1=claim-in-progress, v>0 = row v-1 (zero-init only).

#define HID  64
#define CAP1 2048   // compact rows for F2 (layer-1 outputs)
#define CAP2 512    // compact rows for F1 (layer-2 outputs)
#define RB1  128    // per-row in-edge bucket depth, layer 1
#define RB2  128    // per-row in-edge bucket depth, layer 2
#define CL3  2048   // layer-3 edge list capacity
#define VE   8      // edges per thread in scans
#define TPB  256
#define TT   1024   // threads in fused l2tail (16 waves)
#define NW   16

// wave-level dtype probe: high dwords of first 64 entries all zero -> int64
__device__ __forceinline__ int detect64(const void* ei) {
  const unsigned* e32 = (const unsigned*)ei;
  int lane = threadIdx.x & 63;
  bool z = (e32[2 * lane + 1] == 0u);
  return (__ballot(z) == ~0ull) ? 1 : 0;
}

__device__ __forceinline__ int ld_src(const void* ei, int is64, long long e) {
  return is64 ? (int)((const unsigned*)ei)[e << 1] : ((const int*)ei)[e];
}

// load up to VE dst values from the raw edge index (scanF1 only)
__device__ __forceinline__ int load_dsts(const void* ei, long long E, long long base,
                                         int is64, int d[VE]) {
  int n = (int)((E - base) < VE ? (E - base) : VE);
  if (is64) {
    const unsigned long long* p = (const unsigned long long*)ei + E + base;
    if (n == VE && (((E + base) & 1) == 0)) {
      const ulonglong2* q = (const ulonglong2*)p;
#pragma unroll
      for (int k = 0; k < VE / 2; ++k) {
        ulonglong2 v = q[k];
        d[2 * k] = (int)(unsigned)v.x; d[2 * k + 1] = (int)(unsigned)v.y;
      }
    } else {
      for (int k = 0; k < n; ++k) d[k] = (int)(unsigned)p[k];
    }
  } else {
    const int* p = (const int*)ei + E + base;
    if (n == VE && (((E + base) & 3) == 0)) {
      const int4* q = (const int4*)p;
#pragma unroll
      for (int k = 0; k < VE / 4; ++k) {
        int4 v = q[k];
        d[4 * k] = v.x; d[4 * k + 1] = v.y; d[4 * k + 2] = v.z; d[4 * k + 3] = v.w;
      }
    } else {
      for (int k = 0; k < n; ++k) d[k] = p[k];
    }
  }
  return n;
}

// load up to VE dst values from the compacted int32 array (scans 2-4)
__device__ __forceinline__ int load_dsts32(const int* dst32, long long E,
                                           long long base, int d[VE]) {
  int n = (int)((E - base) < VE ? (E - base) : VE);
  if (n == VE) {  // base is a multiple of VE -> 16B aligned
    int4 a = ((const int4*)(dst32 + base))[0];
    int4 b = ((const int4*)(dst32 + base))[1];
    d[0] = a.x; d[1] = a.y; d[2] = a.z; d[3] = a.w;
    d[4] = b.x; d[5] = b.y; d[6] = b.z; d[7] = b.w;
  } else {
    for (int k = 0; k < n; ++k) d[k] = dst32[base + k];
  }
  return n;
}

// F1 discovery (dst == n0) + n0 seeding + dst32 compaction + layer-3 list.
__global__ void k_scanF1(const void* ei, int E, const int* nidx_p, int* dst32,
                         int* slot2, int* node2, int* cnt2, int* l3, int* ec3) {
  int is64 = detect64(ei);
  int nidx = *nidx_p;
  if (blockIdx.x == 0 && threadIdx.x == 0) {  // seed n0 into F1 (CAS-safe)
    if (atomicCAS(&slot2[nidx], 0, -1) == 0) {
      int p = atomicAdd(cnt2, 1) & (CAP2 - 1);
      slot2[nidx] = p + 1; node2[p] = nidx;
    }
  }
  long long base = ((long long)blockIdx.x * TPB + threadIdx.x) * VE;
  if (base >= E) return;
  int d[VE];
  int n = load_dsts(ei, E, base, is64, d);
  if (n == VE) {
    ((int4*)(dst32 + base))[0] = make_int4(d[0], d[1], d[2], d[3]);
    ((int4*)(dst32 + base))[1] = make_int4(d[4], d[5], d[6], d[7]);
  } else {
    for (int k = 0; k < n; ++k) dst32[base + k] = d[k];
  }
  for (int k = 0; k < n; ++k) {
    if (d[k] == nidx) {
      int s = ld_src(ei, is64, base + k);
      if (atomicCAS(&slot2[s], 0, -1) == 0) {
        int p = atomicAdd(cnt2, 1) & (CAP2 - 1);
        slot2[s] = p + 1; node2[p] = s;
      }
      int q = atomicAdd(ec3, 1);
      if (q < CL3) l3[q] = s;
    }
  }
}

// F2 discovery: prologue propagates F1 -> slot1 (+need); main loop claims
// sources of F1-dst edges and buckets them per F1 row. slot1 VALUES are
// never read in this dispatch, so cross-block CAS claims are safe.
__global__ void k_scanF2(const void* ei, int E, const int* dst32,
                         const int* slot2, const int* node2, const int* cnt2,
                         int* slot1, int* node1, int* need, int* cnt1,
                         int* rc2, int* bl2) {
  int rows2 = min(*cnt2, CAP2);
  for (int r = threadIdx.x; r < rows2; r += TPB) {
    int i = node2[r];
    need[i] = 1;
    if (atomicCAS(&slot1[i], 0, -1) == 0) {
      int p = atomicAdd(cnt1, 1) & (CAP1 - 1);
      slot1[i] = p + 1; node1[p] = i;
    }
  }
  int is64 = detect64(ei);
  long long base = ((long long)blockIdx.x * TPB + threadIdx.x) * VE;
  if (base >= E) return;
  int d[VE];
  int n = load_dsts32(dst32, E, base, d);
  for (int k = 0; k < n; ++k) {
    int sv = slot2[d[k]];
    if (sv > 0) {
      int ad = sv - 1;
      int s = ld_src(ei, is64, base + k);
      need[s] = 1;
      if (atomicCAS(&slot1[s], 0, -1) == 0) {
        int p = atomicAdd(cnt1, 1) & (CAP1 - 1);
        slot1[s] = p + 1; node1[p] = s;
      }
      int q = atomicAdd(&rc2[ad], 1);
      if (q < RB2) bl2[ad * RB2 + q] = s;
    }
  }
}

// S marking + layer-1 buckets: edges with dst in F2.
__global__ void k_scanS(const void* ei, int E, const int* dst32,
                        const int* slot1, int* need, int* rc1, int* bl1) {
  int is64 = detect64(ei);
  long long base = ((long long)blockIdx.x * TPB + threadIdx.x) * VE;
  if (base >= E) return;
  int d[VE];
  int n = load_dsts32(dst32, E, base, d);
  for (int k = 0; k < n; ++k) {
    int sv = slot1[d[k]];
    if (sv > 0) {
      int ad = sv - 1;
      int s = ld_src(ei, is64, base + k);
      need[s] = 1;
      int q = atomicAdd(&rc1[ad], 1);
      if (q < RB1) bl1[ad * RB1 + q] = s;
    }
  }
}

// need-filtered degree histogram (~80K atomics over ~5K addresses)
__global__ void k_scanDeg(int E, const int* dst32, const int* need, int* deg) {
  long long base = ((long long)blockIdx.x * TPB + threadIdx.x) * VE;
  if (base >= E) return;
  int d[VE];
  int n = load_dsts32(dst32, E, base, d);
  for (int k = 0; k < n; ++k)
    if (need[d[k]]) atomicAdd(&deg[d[k]], 1);
}

// layer 1, one wave per F2 row (factorized: neighbor-sum then one matvec).
__global__ void k_l1(const float* __restrict__ x, const float* __restrict__ W1,
                     const float* __restrict__ b1, const int* __restrict__ deg,
                     const int* __restrict__ node1, const int* __restrict__ cnt1,
                     const int* __restrict__ rc1, const int* __restrict__ bl1,
                     float* __restrict__ h1c) {
  int w = blockIdx.x * 4 + (threadIdx.x >> 6);
  int lane = threadIdx.x & 63;
  int rows = min(*cnt1, CAP1);
  if (w >= rows) return;
  int i = node1[w];
  float di = 1.0f / sqrtf((float)(deg[i] + 1));
  int cnt = min(rc1[w], RB1);
  float ax = 0.f, ay = 0.f, az = 0.f, aw = 0.f;
  for (int j = lane; j < cnt; j += 64) {
    int s = bl1[w * RB1 + j];
    float c = (1.0f / sqrtf((float)(deg[s] + 1))) * di;
    float4 xv = ((const float4*)x)[s];
    ax += c * xv.x; ay += c * xv.y; az += c * xv.z; aw += c * xv.w;
  }
#pragma unroll
  for (int t = 1; t < 64; t <<= 1) {
    ax += __shfl_xor(ax, t); ay += __shfl_xor(ay, t);
    az += __shfl_xor(az, t); aw += __shfl_xor(aw, t);
  }
  float4 xi = ((const float4*)x)[i];
  float dd = di * di;
  ax += dd * xi.x; ay += dd * xi.y; az += dd * xi.z; aw += dd * xi.w;
  float v = ax * W1[lane] + ay * W1[64 + lane] + az * W1[128 + lane] +
            aw * W1[192 + lane] + b1[lane];
  h1c[w * HID + lane] = v > 0.f ? v : 0.f;
}

// fused layer-2 + layer-3 + head. ONE block, 16 waves (~1 F1 row per wave).
// All gathers 8/4-batched for miss-level parallelism; NO early returns
// (loop guards only) so every thread reaches every barrier.
__global__ __launch_bounds__(TT) void k_l2tail(
    const float* __restrict__ W2, const float* __restrict__ b2,
    const int* __restrict__ deg, const int* __restrict__ node2,
    const int* __restrict__ cnt2, const int* __restrict__ slot1,
    const int* __restrict__ rc2, const int* __restrict__ bl2,
    const float* __restrict__ h1c, float* __restrict__ h2c,
    const int* __restrict__ nidx_p, const int* __restrict__ slot2,
    const int* __restrict__ l3, const int* __restrict__ ec3,
    const float* __restrict__ W3, const float* __restrict__ b3,
    const float* __restrict__ Wp, const float* __restrict__ bp,
    const float* __restrict__ Wa, const float* __restrict__ ba,
    const float* __restrict__ Wm, const float* __restrict__ bm,
    const float* __restrict__ Wg, const float* __restrict__ bg,
    const float* __restrict__ Wt, const float* __restrict__ bt,
    float* __restrict__ out) {
  __shared__ float h2s[64][HID];   // F1 h2 rows (spill to h2c >= 64)
  __shared__ float sh[NW][HID];    // per-wave row buffer for W2 matvec
  __shared__ float part[NW][HID];  // cross-wave reduce buffer
  __shared__ float g3[HID];
  __shared__ float h3[HID];
  __shared__ float p[HID];
  __shared__ int   ssl[64];
  __shared__ float scc[64];
  int tid = threadIdx.x, wv = tid >> 6, lane = tid & 63;
  int nidx = *nidx_p;
  int rows = min(*cnt2, CAP2);

  // ---- phase A: layer 2, one wave per F1 row ----
  for (int w = wv; w < rows; w += NW) {
    int i = node2[w];
    float di = 1.0f / sqrtf((float)(deg[i] + 1));
    int cnt = min(rc2[w], RB2);
    float acc = 0.f;
    for (int j0 = 0; j0 < cnt; j0 += 64) {
      int nb = min(64, cnt - j0);
      int sl = 0; float c = 0.f;
      if (lane < nb) {
        int s = bl2[w * RB2 + j0 + lane];
        sl = slot1[s] - 1;
        c = (1.0f / sqrtf((float)(deg[s] + 1))) * di;
      }
      int j = 0;
      for (; j + 8 <= nb; j += 8) {
        int r0 = __shfl(sl, j + 0), r1 = __shfl(sl, j + 1);
        int r2 = __shfl(sl, j + 2), r3 = __shfl(sl, j + 3);
        int r4 = __shfl(sl, j + 4), r5 = __shfl(sl, j + 5);
        int r6 = __shfl(sl, j + 6), r7 = __shfl(sl, j + 7);
        float v0 = h1c[r0 * HID + lane];
        float v1 = h1c[r1 * HID + lane];
        float v2 = h1c[r2 * HID + lane];
        float v3 = h1c[r3 * HID + lane];
        float v4 = h1c[r4 * HID + lane];
        float v5 = h1c[r5 * HID + lane];
        float v6 = h1c[r6 * HID + lane];
        float v7 = h1c[r7 * HID + lane];
        acc += __shfl(c, j + 0) * v0 + __shfl(c, j + 1) * v1 +
               __shfl(c, j + 2) * v2 + __shfl(c, j + 3) * v3 +
               __shfl(c, j + 4) * v4 + __shfl(c, j + 5) * v5 +
               __shfl(c, j + 6) * v6 + __shfl(c, j + 7) * v7;
      }
      for (; j < nb; ++j)
        acc += __shfl(c, j) * h1c[__shfl(sl, j) * HID + lane];
    }
    acc += di * di * h1c[(slot1[i] - 1) * HID + lane];
    sh[wv][lane] = acc;  // same-wave write->read (lockstep)
    float v = b2[lane];
#pragma unroll 16
    for (int k = 0; k < HID; ++k) v += sh[wv][k] * W2[k * HID + lane];
    v = v > 0.f ? v : 0.f;
    if (w < 64) h2s[w][lane] = v; else h2c[w * HID + lane] = v;
  }
  __syncthreads();

  // ---- phase B: layer-3 aggregate over l3 list (batched), 16 waves ----
  float dn = 1.0f / sqrtf((float)(deg[nidx] + 1));
  int cnt = min(*ec3, CL3);
  float acc = 0.f;
  for (int j0 = 0; j0 < cnt; j0 += 64) {
    int nb = min(64, cnt - j0);
    if (tid < nb) {
      int s = l3[j0 + tid];
      ssl[tid] = slot2[s] - 1;
      scc[tid] = (1.0f / sqrtf((float)(deg[s] + 1))) * dn;
    }
    __syncthreads();
    int j = wv;
    for (; j + 48 < nb; j += 64) {  // 4 batched rows per wave
      int r0 = ssl[j], r1 = ssl[j + 16], r2 = ssl[j + 32], r3 = ssl[j + 48];
      float v0 = (r0 < 64) ? h2s[r0][lane] : h2c[r0 * HID + lane];
      float v1 = (r1 < 64) ? h2s[r1][lane] : h2c[r1 * HID + lane];
      float v2 = (r2 < 64) ? h2s[r2][lane] : h2c[r2 * HID + lane];
      float v3 = (r3 < 64) ? h2s[r3][lane] : h2c[r3 * HID + lane];
      acc += scc[j] * v0 + scc[j + 16] * v1 + scc[j + 32] * v2 +
             scc[j + 48] * v3;
    }
    for (; j < nb; j += NW) {
      int r = ssl[j];
      float hv = (r < 64) ? h2s[r][lane] : h2c[r * HID + lane];
      acc += scc[j] * hv;
    }
    __syncthreads();
  }
  part[wv][lane] = acc;
  __syncthreads();
  if (wv == 0) {
    float a = 0.f;
#pragma unroll
    for (int u = 0; u < NW; ++u) a += part[u][lane];
    int r = slot2[nidx] - 1;
    float hv = (r < 64) ? h2s[r][lane] : h2c[r * HID + lane];
    g3[lane] = a + dn * dn * hv;
  }
  __syncthreads();
  {  // h3 = relu(g3 @ W3 + b3), k-split over 16 waves (4 k each)
    int k0 = wv * 4;
    float v = g3[k0] * W3[k0 * HID + lane] +
              g3[k0 + 1] * W3[(k0 + 1) * HID + lane] +
              g3[k0 + 2] * W3[(k0 + 2) * HID + lane] +
              g3[k0 + 3] * W3[(k0 + 3) * HID + lane];
    part[wv][lane] = v;
  }
  __syncthreads();
  if (wv == 0) {
    float v = b3[lane];
#pragma unroll
    for (int u = 0; u < NW; ++u) v += part[u][lane];
    h3[lane] = v > 0.f ? v : 0.f;
  }
  __syncthreads();
  {  // p = relu(h3 @ Wp + bp), k-split over 16 waves
    int k0 = wv * 4;
    float v = h3[k0] * Wp[k0 * HID + lane] +
              h3[k0 + 1] * Wp[(k0 + 1) * HID + lane] +
              h3[k0 + 2] * Wp[(k0 + 2) * HID + lane] +
              h3[k0 + 3] * Wp[(k0 + 3) * HID + lane];
    part[wv][lane] = v;
  }
  __syncthreads();
  if (wv == 0) {
    float v = bp[lane];
#pragma unroll
    for (int u = 0; u < NW; ++u) v += part[u][lane];
    p[lane] = v > 0.f ? v : 0.f;
  }
  __syncthreads();
  if (tid < 4) {
    float o = ba[tid];
#pragma unroll 8
    for (int k = 0; k < HID; ++k) o += p[k] * Wa[k * 4 + tid];
    out[tid] = o;
  } else if (tid < 6) {
    int c = tid - 4; float o = bm[c];
#pragma unroll 8
    for (int k = 0; k < HID; ++k) o += p[k] * Wm[k * 2 + c];
    out[tid] = o;
  } else if (tid < 9) {
    int c = tid - 6; float o = bg[c];
#pragma unroll 8
    for (int k = 0; k < HID; ++k) o += p[k] * Wg[k * 3 + c];
    out[tid] = o;
  } else if (tid < 19) {
    int c = tid - 9; float o = bt[c];
#pragma unroll 8
    for (int k = 0; k < HID; ++k) o += p[k] * Wt[k * 10 + c];
    out[tid] = o;
  }
}

extern "C" void kernel_launch(void* const* d_in, const int* in_sizes, int n_in,
                              void* d_out, int out_size, void* d_ws, size_t ws_size,
                              hipStream_t stream) {
  const float* x  = (const float*)d_in[0];
  const void*  ei = d_in[1];
  const int* nidx = (const int*)d_in[2];
  const float* W1 = (const float*)d_in[3];
  const float* b1 = (const float*)d_in[4];
  const float* W2 = (const float*)d_in[5];
  const float* b2 = (const float*)d_in[6];
  const float* W3 = (const float*)d_in[7];
  const float* b3 = (const float*)d_in[8];
  const float* Wp = (const float*)d_in[9];
  const float* bp = (const float*)d_in[10];
  const float* Wa = (const float*)d_in[11];
  const float* ba = (const float*)d_in[12];
  const float* Wm = (const float*)d_in[13];
  const float* bm = (const float*)d_in[14];
  const float* Wg = (const float*)d_in[15];
  const float* bg = (const float*)d_in[16];
  const float* Wt = (const float*)d_in[17];
  const float* bt = (const float*)d_in[18];
  float* out = (float*)d_out;

  int N = in_sizes[0] / 4;   // 100000
  int E = in_sizes[1] / 2;   // 1600000

  char* w = (char*)d_ws;
  size_t o = 0;
  auto take = [&](size_t bytes) -> void* {
    void* p = w + o;
    o += (bytes + 255) & ~(size_t)255;
    return p;
  };
  // single zero region: counters, deg, need, rc1, rc2, slot1, slot2
  size_t zeroInts = (size_t)8 + 2 * (size_t)N + CAP1 + CAP2 + 2 * (size_t)N;
  int* zr = (int*)take(zeroInts * 4);
  int* cnt1  = zr + 0;
  int* cnt2  = zr + 1;
  int* ec3   = zr + 2;
  int* deg   = zr + 8;
  int* need  = deg + N;
  int* rc1   = need + N;
  int* rc2   = rc1 + CAP1;
  int* slot1 = rc2 + CAP2;
  int* slot2 = slot1 + N;
  int*   dst32 = (int*)take((size_t)E * 4);
  int*   node1 = (int*)take((size_t)CAP1 * 4);
  int*   node2 = (int*)take((size_t)CAP2 * 4);
  int*   bl1   = (int*)take((size_t)CAP1 * RB1 * 4);
  int*   bl2   = (int*)take((size_t)CAP2 * RB2 * 4);
  int*   l3    = (int*)take((size_t)CL3 * 4);
  float* h1c   = (float*)take((size_t)CAP1 * HID * 4);
  float* h2c   = (float*)take((size_t)CAP2 * HID * 4);

  int gS = (int)(((long long)E + TPB * VE - 1) / (TPB * VE));

  hipMemsetAsync(zr, 0x00, zeroInts * 4, stream);
  k_scanF1 <<<gS, TPB, 0, stream>>>(ei, E, nidx, dst32, slot2, node2, cnt2, l3, ec3);
  k_scanF2 <<<gS, TPB, 0, stream>>>(ei, E, dst32, slot2, node2, cnt2,
                                    slot1, node1, need, cnt1, rc2, bl2);
  k_scanS  <<<gS, TPB, 0, stream>>>(ei, E, dst32, slot1, need, rc1, bl1);
  k_scanDeg<<<gS, TPB, 0, stream>>>(E, dst32, need, deg);
  k_l1     <<<CAP1 / 4, TPB, 0, stream>>>(x, W1, b1, deg, node1, cnt1, rc1, bl1, h1c);
  k_l2tail <<<1, TT, 0, stream>>>(W2, b2, deg, node2, cnt2, slot1, rc2, bl2,
                                  h1c, h2c, nidx, slot2, l3, ec3, W3, b3,
                                  Wp, bp, Wa, ba, Wm, bm, Wg, bg, Wt, bt, out);
}